// Round 4
// baseline (681.551 us; speedup 1.0000x reference)
//
#include <hip/hip_runtime.h>
#include <hip/hip_bf16.h>
#include <cstdint>
#include <cstddef>

typedef __bf16 bf16x2 __attribute__((ext_vector_type(2)));
typedef __bf16 bf16x8 __attribute__((ext_vector_type(8)));
typedef float f32x4 __attribute__((ext_vector_type(4)));

__device__ __forceinline__ void gl_lds16(const __bf16* g, __bf16* l) {
    __builtin_amdgcn_global_load_lds(
        (const __attribute__((address_space(1))) unsigned int*)g,
        (__attribute__((address_space(3))) unsigned int*)l, 16, 0, 0);
}

// load 8 consecutive A elements at p, as bf16x8 (f32 converts, bf16 passes through)
template <typename AT>
__device__ __forceinline__ bf16x8 loadA8(const AT* p) {
    if constexpr (sizeof(AT) == 4) {
        float4 u = *(const float4*)p;
        float4 v = *(const float4*)(p + 4);
        return (bf16x8){(__bf16)u.x, (__bf16)u.y, (__bf16)u.z, (__bf16)u.w,
                        (__bf16)v.x, (__bf16)v.y, (__bf16)v.z, (__bf16)v.w};
    } else {
        return *(const bf16x8*)p;
    }
}

// ---------------------------------------------------------------- U-set marking
__global__ __launch_bounds__(256) void mark_idx_kernel(const int* __restrict__ idx,
                                                       int* __restrict__ flagIdx,
                                                       int* __restrict__ flagU, int B) {
    int t = blockIdx.x * 256 + threadIdx.x;
    if (t < B) {
        int n = idx[t];
        flagIdx[n] = 1;
        flagU[n] = 1;
    }
}

// histogram of dst + mark sources of idx-edges (one pass over edges)
__global__ __launch_bounds__(256) void hist_mark_kernel(const int* __restrict__ esrc,
                                                        const int* __restrict__ edst,
                                                        const int* __restrict__ flagIdx,
                                                        int* __restrict__ deg,
                                                        int* __restrict__ flagU, int E) {
    int e = blockIdx.x * 256 + threadIdx.x;
    if (e < E) {
        int d = edst[e];
        atomicAdd(&deg[d], 1);
        if (flagIdx[d]) flagU[esrc[e]] = 1;
    }
}

__global__ __launch_bounds__(256) void compact_kernel(const int* __restrict__ flagU,
                                                      int* __restrict__ U,
                                                      int* __restrict__ nU, int N) {
    int i = blockIdx.x * 256 + threadIdx.x;
    if (i < N && flagU[i]) U[atomicAdd(nU, 1)] = i;
}

// ---------------------------------------------------------------- scan (1 block, 8/thread)
__global__ __launch_bounds__(1024) void scan8_kernel(const int* __restrict__ deg,
                                                     int* __restrict__ off, int n) {
    __shared__ int wsum[16];
    int tid = threadIdx.x, lane = tid & 63, wid = tid >> 6;
    if (tid == 0) off[0] = 0;
    int carry = 0;
    int nchunk = (n + 8191) >> 13;
    for (int c = 0; c < nchunk; ++c) {
        int base = (c << 13) + tid * 8;
        int4 a = *(const int4*)(deg + base);
        int4 b = *(const int4*)(deg + base + 4);
        int s[8];
        s[0] = a.x; s[1] = s[0] + a.y; s[2] = s[1] + a.z; s[3] = s[2] + a.w;
        s[4] = s[3] + b.x; s[5] = s[4] + b.y; s[6] = s[5] + b.z; s[7] = s[6] + b.w;
        int x = s[7];
        for (int o = 1; o < 64; o <<= 1) {
            int t = __shfl_up(x, o, 64);
            if (lane >= o) x += t;
        }
        if (lane == 63) wsum[wid] = x;
        __syncthreads();
        if (wid == 0 && lane < 16) {
            int w = wsum[lane];
            for (int o = 1; o < 16; o <<= 1) {
                int t = __shfl_up(w, o, 64);
                if (lane >= o) w += t;
            }
            wsum[lane] = w;
        }
        __syncthreads();
        int pre = carry + (wid ? wsum[wid - 1] : 0) + (x - s[7]);
#pragma unroll
        for (int i = 0; i < 8; ++i)
            if (base + i < n) off[base + i + 1] = pre + s[i];
        carry += wsum[15];
        __syncthreads();
    }
}

__global__ __launch_bounds__(256) void scatter_kernel(const int* __restrict__ src,
                                                      const int* __restrict__ dst,
                                                      const int* __restrict__ off,
                                                      int* __restrict__ cursor,
                                                      int* __restrict__ srcs, int E) {
    int e = blockIdx.x * 256 + threadIdx.x;
    if (e < E) {
        int d = dst[e];
        int p = off[d] + atomicAdd(&cursor[d], 1);
        srcs[p] = src[e];
    }
}

// ---------------------------------------------------------------- weight prep
// w0t: [512,1024] bf16 rows ordered k,v,q,s ; w1t: [512,128] ; b0,b1: [512] f32 same order
__global__ __launch_bounds__(256) void pack_w_kernel(const float* __restrict__ wq0, const float* __restrict__ wk0,
                                                     const float* __restrict__ wv0, const float* __restrict__ ws0,
                                                     const float* __restrict__ wq1, const float* __restrict__ wk1,
                                                     const float* __restrict__ wv1, const float* __restrict__ ws1,
                                                     const float* __restrict__ bq0, const float* __restrict__ bk0,
                                                     const float* __restrict__ bv0, const float* __restrict__ bs0,
                                                     const float* __restrict__ bq1, const float* __restrict__ bk1,
                                                     const float* __restrict__ bv1, const float* __restrict__ bs1,
                                                     __bf16* __restrict__ w0t, __bf16* __restrict__ w1t,
                                                     float* __restrict__ b0, float* __restrict__ b1) {
    int i = blockIdx.x * 256 + threadIdx.x;
    const int S0 = 512 * 1024, S1 = 512 * 128;
    if (i < S0) {
        int n = i >> 10, k = i & 1023;
        int sel = n >> 7, c = n & 127;
        const float* w = (sel == 0) ? wk0 : (sel == 1) ? wv0 : (sel == 2) ? wq0 : ws0;
        w0t[i] = (__bf16)w[(size_t)k * 128 + c];
    } else if (i < S0 + S1) {
        int j = i - S0;
        int n = j >> 7, k = j & 127;
        int sel = n >> 7, c = n & 127;
        const float* w = (sel == 0) ? wk1 : (sel == 1) ? wv1 : (sel == 2) ? wq1 : ws1;
        w1t[j] = (__bf16)w[(size_t)k * 128 + c];
    } else if (i < S0 + S1 + 512) {
        int t = i - S0 - S1;
        int sel = t >> 7, c = t & 127;
        const float* b = (sel == 0) ? bk0 : (sel == 1) ? bv0 : (sel == 2) ? bq0 : bs0;
        b0[t] = b[c];
    } else if (i < S0 + S1 + 1024) {
        int t = i - S0 - S1 - 512;
        int sel = t >> 7, c = t & 127;
        const float* b = (sel == 0) ? bk1 : (sel == 1) ? bv1 : (sel == 2) ? bq1 : bs1;
        b1[t] = b[c];
    }
}

// ---------------------------------------------------------------- dual-sector MFMA GEMM, double-buffered
// sector = blockIdx.x>>1 : 0 -> Bt rows [0,256)   -> outb (bf16), rows rl0/n0
//                          1 -> Bt rows [256,512) -> outf (f32),  rows rl1/n1
// nbase = (blockIdx.x&1)*128. A is f32 (layer0) or bf16 (layer1); converted to bf16 in staging.
// 128x128 tile, 4 waves 2x2, 16x16x32 MFMA. K-loop double-buffers LDS: B via global_load_lds
// prefetch, A via VGPR prefetch + ds_write. Pre-barrier vmcnt(0) drain overlaps compute.
template <typename AT>
__global__ __launch_bounds__(256) void gemm_dual_kernel(const AT* __restrict__ A,
                                                        const __bf16* __restrict__ Bt,
                                                        const float* __restrict__ bias,
                                                        __bf16* __restrict__ outb,
                                                        float* __restrict__ outf,
                                                        const int* __restrict__ rl0,
                                                        const int* __restrict__ np0, int ns0,
                                                        const int* __restrict__ rl1,
                                                        const int* __restrict__ np1, int ns1,
                                                        int K) {
    __shared__ __align__(16) __bf16 Asl[2][128 * 32];
    __shared__ __align__(16) __bf16 Bsl[2][128 * 32];
    const int sector = blockIdx.x >> 1;
    const int nbase = (blockIdx.x & 1) << 7;
    const int* rowlist = sector ? rl1 : rl0;
    const int* nptr = sector ? np1 : np0;
    const int nrows = nptr ? *nptr : (sector ? ns1 : ns0);
    if (nrows <= 0) return;
    const __bf16* BT = Bt + (size_t)(sector ? 256 : 0) * K;
    const float* bs = bias + (sector ? 256 : 0);
    const int ntiles = (nrows + 127) >> 7;
    const int nk = K >> 5;

    const int tid = threadIdx.x;
    const int lane = tid & 63, wid = tid >> 6;
    const int wm = wid >> 1, wn = wid & 1;
    const int fr = lane & 15, quad = lane >> 4;
    const int rr = (wid << 4) + (lane >> 2);   // staging row within 64-row round
    const int kc8 = (lane & 3) << 3;           // k-offset in elements (8/lane)

    // B staging global pointers (fixed across m-tiles) and wave-uniform LDS offsets
    const __bf16* gB0 = BT + (size_t)(nbase + rr) * K + kc8;
    const __bf16* gB1 = BT + (size_t)(nbase + 64 + rr) * K + kc8;
    const int ldsBoff0 = (wid << 4) * 32;
    const int ldsBoff1 = (64 + (wid << 4)) * 32;
    // A staging LDS offsets (per-lane, ds_write)
    const int ldsAoff0 = rr * 32 + kc8;
    const int ldsAoff1 = (64 + rr) * 32 + kc8;

    for (int mt = blockIdx.y; mt < ntiles; mt += gridDim.y) {
        const int mbase = mt << 7;
        int lr0 = mbase + rr;        if (lr0 >= nrows) lr0 = nrows - 1;
        int lr1 = mbase + 64 + rr;   if (lr1 >= nrows) lr1 = nrows - 1;
        const int gr0 = rowlist ? rowlist[lr0] : lr0;
        const int gr1 = rowlist ? rowlist[lr1] : lr1;
        const AT* gA0 = A + (size_t)gr0 * K + kc8;
        const AT* gA1 = A + (size_t)gr1 * K + kc8;

        f32x4 acc[4][4];
#pragma unroll
        for (int i = 0; i < 4; i++)
#pragma unroll
            for (int j = 0; j < 4; j++) acc[i][j] = (f32x4){0.f, 0.f, 0.f, 0.f};

        // K prologue: stage slice 0 into buffer 0
        gl_lds16(gB0, &Bsl[0][ldsBoff0]);
        gl_lds16(gB1, &Bsl[0][ldsBoff1]);
        {
            bf16x8 p0 = loadA8(gA0);
            bf16x8 p1 = loadA8(gA1);
            *(bf16x8*)&Asl[0][ldsAoff0] = p0;
            *(bf16x8*)&Asl[0][ldsAoff1] = p1;
        }
        __syncthreads();

        for (int kk = 0; kk < nk; ++kk) {
            const int p = kk & 1, q = p ^ 1;
            const bool more = (kk + 1) < nk;
            bf16x8 n0, n1;
            if (more) {
                const int ko = (kk + 1) << 5;
                gl_lds16(gB0 + ko, &Bsl[q][ldsBoff0]);
                gl_lds16(gB1 + ko, &Bsl[q][ldsBoff1]);
                n0 = loadA8(gA0 + ko);
                n1 = loadA8(gA1 + ko);
            }
            bf16x8 af[4], bfr[4];
#pragma unroll
            for (int mi = 0; mi < 4; mi++)
                af[mi] = *(const bf16x8*)&Asl[p][(wm * 64 + mi * 16 + fr) * 32 + quad * 8];
#pragma unroll
            for (int ni = 0; ni < 4; ni++)
                bfr[ni] = *(const bf16x8*)&Bsl[p][(wn * 64 + ni * 16 + fr) * 32 + quad * 8];
#pragma unroll
            for (int mi = 0; mi < 4; mi++)
#pragma unroll
                for (int ni = 0; ni < 4; ni++)
                    acc[mi][ni] = __builtin_amdgcn_mfma_f32_16x16x32_bf16(af[mi], bfr[ni], acc[mi][ni], 0, 0, 0);
            if (more) {
                *(bf16x8*)&Asl[q][ldsAoff0] = n0;
                *(bf16x8*)&Asl[q][ldsAoff1] = n1;
            }
            __syncthreads();
        }

#pragma unroll
        for (int mi = 0; mi < 4; mi++)
#pragma unroll
            for (int ni = 0; ni < 4; ni++) {
                int rl = wm * 64 + mi * 16 + quad * 4;
                int cl = wn * 64 + ni * 16 + fr;
                float b = bs[nbase + cl];
                int gcol = nbase + cl;
#pragma unroll
                for (int r = 0; r < 4; r++) {
                    int lr = mbase + rl + r;
                    if (lr < nrows) {
                        int gr = rowlist ? rowlist[lr] : lr;
                        float v = acc[mi][ni][r] + b;
                        if (sector == 0) outb[(size_t)gr * 256 + gcol] = (__bf16)v;
                        else             outf[(size_t)gr * 256 + gcol] = v;
                    }
                }
            }
    }
}

// ---------------------------------------------------------------- per-dst online-softmax attention
// q,s f32 from qs[node][0:128 / 128:256]; k,v bf16 from kvb[src][0:128 / 128:256].
// mode 1: out = relu(agg+s) bf16 by node ; mode 0: out f32 by slot.
__global__ __launch_bounds__(256) void attn_kernel(const float* __restrict__ qs,
                                                   const __bf16* __restrict__ kvb,
                                                   const int* __restrict__ off,
                                                   const int* __restrict__ srcs,
                                                   const int* __restrict__ nodelist,
                                                   const int* __restrict__ nptr, int nstatic,
                                                   __bf16* __restrict__ outb,
                                                   float* __restrict__ outf, int mode) {
    int n = nptr ? *nptr : nstatic;
    int lane = threadIdx.x & 63;
    int w0 = blockIdx.x * 4 + (threadIdx.x >> 6);
    int nw = gridDim.x * 4;
    const float scale = 0.08838834764831845f;  // 1/sqrt(128)
    for (int w = w0; w < n; w += nw) {
        int node = nodelist ? nodelist[w] : w;
        const float* bq = qs + (size_t)node * 256;
        float2 q = *(const float2*)(bq + 2 * lane);
        float2 s = *(const float2*)(bq + 128 + 2 * lane);
        int e0 = off[node], e1 = off[node + 1];
        float m = -INFINITY, l = 0.f;
        float ax = 0.f, ay = 0.f;
        bf16x2 kc = {(__bf16)0.f, (__bf16)0.f}, vc = kc;
        if (e0 < e1) {
            const __bf16* p = kvb + (size_t)srcs[e0] * 256;
            kc = *(const bf16x2*)(p + 2 * lane);
            vc = *(const bf16x2*)(p + 128 + 2 * lane);
        }
        for (int e = e0; e < e1; ++e) {
            bf16x2 kn = {(__bf16)0.f, (__bf16)0.f}, vn = kn;
            if (e + 1 < e1) {  // prefetch next edge before the serial chain
                const __bf16* p = kvb + (size_t)srcs[e + 1] * 256;
                kn = *(const bf16x2*)(p + 2 * lane);
                vn = *(const bf16x2*)(p + 128 + 2 * lane);
            }
            float t = q.x * (float)kc.x + q.y * (float)kc.y;
#pragma unroll
            for (int o = 32; o > 0; o >>= 1) t += __shfl_xor(t, o, 64);
            float sc = t * scale;
            float mn = fmaxf(m, sc);
            float al = __expf(m - mn);
            float ee = __expf(sc - mn);
            ax = ax * al + ee * (float)vc.x;
            ay = ay * al + ee * (float)vc.y;
            l = l * al + ee;
            m = mn;
            kc = kn; vc = vn;
        }
        float inv = 1.f / (l + 1e-16f);
        float ox = ax * inv + s.x, oy = ay * inv + s.y;
        if (mode) {
            bf16x2 o2 = {(__bf16)fmaxf(ox, 0.f), (__bf16)fmaxf(oy, 0.f)};
            *(bf16x2*)(outb + (size_t)node * 128 + 2 * lane) = o2;
        } else {
            float2 o2 = {fmaxf(ox, 0.f), fmaxf(oy, 0.f)};
            *(float2*)(outf + (size_t)w * 128 + 2 * lane) = o2;
        }
    }
}

// ---------------------------------------------------------------- MLP head: 128 -> 128 -> 64 -> 1 sigmoid
__global__ __launch_bounds__(128) void mlp_kernel(const float* __restrict__ hbuf,
                                                  const float* __restrict__ mw1, const float* __restrict__ mb1,
                                                  const float* __restrict__ mw2, const float* __restrict__ mb2,
                                                  const float* __restrict__ mw3, const float* __restrict__ mb3,
                                                  float* __restrict__ out, int B) {
    int b = blockIdx.x;
    int t = threadIdx.x;
    if (b >= B) return;
    __shared__ float xr[128], z1[128], z2[64];
    xr[t] = hbuf[(size_t)b * 128 + t];
    __syncthreads();
    float a1 = mb1[t];
#pragma unroll 8
    for (int k = 0; k < 128; ++k) a1 += xr[k] * mw1[k * 128 + t];
    z1[t] = fmaxf(a1, 0.f);
    __syncthreads();
    if (t < 64) {
        float a2 = mb2[t];
#pragma unroll 8
        for (int k = 0; k < 128; ++k) a2 += z1[k] * mw2[k * 64 + t];
        z2[t] = fmaxf(a2, 0.f);
    }
    __syncthreads();
    if (t < 64) {
        float p = z2[t] * mw3[t];
#pragma unroll
        for (int o = 32; o > 0; o >>= 1) p += __shfl_xor(p, o, 64);
        if (t == 0) out[b] = 1.f / (1.f + __expf(-(p + mb3[0])));
    }
}

// ---------------------------------------------------------------- launch
extern "C" void kernel_launch(void* const* d_in, const int* in_sizes, int n_in,
                              void* d_out, int out_size, void* d_ws, size_t ws_size,
                              hipStream_t stream) {
    const float* x   = (const float*)d_in[0];
    const int*   ei  = (const int*)d_in[1];
    const int*   idx = (const int*)d_in[2];
    const float* wq0 = (const float*)d_in[3];
    const float* wk0 = (const float*)d_in[4];
    const float* wv0 = (const float*)d_in[5];
    const float* ws0 = (const float*)d_in[6];
    const float* bq0 = (const float*)d_in[7];
    const float* bk0 = (const float*)d_in[8];
    const float* bv0 = (const float*)d_in[9];
    const float* bs0 = (const float*)d_in[10];
    const float* wq1 = (const float*)d_in[11];
    const float* wk1 = (const float*)d_in[12];
    const float* wv1 = (const float*)d_in[13];
    const float* ws1 = (const float*)d_in[14];
    const float* bq1 = (const float*)d_in[15];
    const float* bk1 = (const float*)d_in[16];
    const float* bv1 = (const float*)d_in[17];
    const float* bs1 = (const float*)d_in[18];
    const float* mw1 = (const float*)d_in[19];
    const float* mb1 = (const float*)d_in[20];
    const float* mw2 = (const float*)d_in[21];
    const float* mb2 = (const float*)d_in[22];
    const float* mw3 = (const float*)d_in[23];
    const float* mb3 = (const float*)d_in[24];
    float* out = (float*)d_out;

    const int Nn = in_sizes[0] / 1024;  // 50000
    const int E  = in_sizes[1] / 2;     // 600000
    const int B  = in_sizes[2];         // 1000
    const int* esrc = ei;
    const int* edst = ei + E;
    const int degPad = ((Nn + 8191) >> 13) << 13;

    uintptr_t base = (uintptr_t)d_ws;
    auto alloc = [&](size_t bytes) -> void* {
        uintptr_t p = (base + 255) & ~(uintptr_t)255;
        base = p + bytes;
        return (void*)p;
    };
    __bf16* kvb  = (__bf16*)alloc((size_t)Nn * 256 * 2);   // 25.6 MB; kv1b aliases (kv0 dead after attn0)
    __bf16* kv1b = kvb;
    float*  qs   = (float*)alloc((size_t)Nn * 256 * 4);    // 51.2 MB; qs1 aliases
    float*  qs1  = qs;
    __bf16* h0b  = (__bf16*)alloc((size_t)Nn * 128 * 2);   // 12.8 MB (only U rows valid)
    float*  hbuf = (float*)alloc((size_t)B * 128 * 4);
    __bf16* w0t  = (__bf16*)alloc(512 * 1024 * 2);
    __bf16* w1t  = (__bf16*)alloc(512 * 128 * 2);
    float*  b0   = (float*)alloc(512 * 4);
    float*  b1   = (float*)alloc(512 * 4);
    // zero region (one memset): deg(padded), cursor, flagIdx, flagU, nU
    int* deg     = (int*)alloc((size_t)degPad * 4);
    int* cursor  = (int*)alloc((size_t)Nn * 4);
    int* flagIdx = (int*)alloc((size_t)Nn * 4);
    int* flagU   = (int*)alloc((size_t)Nn * 4);
    int* nU      = (int*)alloc(256);
    size_t zbytes = (uintptr_t)nU + 256 - (uintptr_t)deg;
    int* off     = (int*)alloc((size_t)(Nn + 1) * 4);
    int* srcs    = (int*)alloc((size_t)E * 4);
    int* U       = (int*)alloc((size_t)Nn * 4);

    hipMemsetAsync(deg, 0, zbytes, stream);

    // ---- U set + CSR
    mark_idx_kernel<<<(B + 255) / 256, 256, 0, stream>>>(idx, flagIdx, flagU, B);
    hist_mark_kernel<<<(E + 255) / 256, 256, 0, stream>>>(esrc, edst, flagIdx, deg, flagU, E);
    scan8_kernel<<<1, 1024, 0, stream>>>(deg, off, Nn);
    scatter_kernel<<<(E + 255) / 256, 256, 0, stream>>>(esrc, edst, off, cursor, srcs, E);
    compact_kernel<<<(Nn + 255) / 256, 256, 0, stream>>>(flagU, U, nU, Nn);

    // ---- weights
    pack_w_kernel<<<(512 * 1024 + 512 * 128 + 1024 + 255) / 256, 256, 0, stream>>>(
        wq0, wk0, wv0, ws0, wq1, wk1, wv1, ws1,
        bq0, bk0, bv0, bs0, bq1, bk1, bv1, bs1, w0t, w1t, b0, b1);

    const int mtiles = (Nn + 127) / 128;  // 391

    // ---- layer 0: sector0 = k|v all rows -> kvb(bf16); sector1 = q|s U rows -> qs(f32)
    gemm_dual_kernel<float><<<dim3(4, mtiles), 256, 0, stream>>>(x, w0t, b0, kvb, qs,
                                                                 nullptr, nullptr, Nn,
                                                                 U, nU, 0, 1024);
    attn_kernel<<<4096, 256, 0, stream>>>(qs, kvb, off, srcs, U, nU, 0, h0b, nullptr, 1);

    // ---- layer 1: sector0 = k|v U rows -> kv1b(bf16); sector1 = q|s idx rows -> qs1(f32)
    gemm_dual_kernel<__bf16><<<dim3(4, 96), 256, 0, stream>>>(h0b, w1t, b1, kv1b, qs1,
                                                              U, nU, 0,
                                                              idx, nullptr, B, 128);
    attn_kernel<<<(B + 3) / 4, 256, 0, stream>>>(qs1, kv1b, off, srcs, idx, nullptr, B, nullptr, hbuf, 0);

    // ---- MLP head
    mlp_kernel<<<B, 128, 0, stream>>>(hbuf, mw1, mb1, mw2, mb2, mw3, mb3, out, B);
}

// Round 5
// 639.602 us; speedup vs baseline: 1.0656x; 1.0656x over previous
//
#include <hip/hip_runtime.h>
#include <hip/hip_bf16.h>
#include <cstdint>
#include <cstddef>

typedef __bf16 bf16x2 __attribute__((ext_vector_type(2)));
typedef __bf16 bf16x8 __attribute__((ext_vector_type(8)));
typedef float f32x4 __attribute__((ext_vector_type(4)));

__device__ __forceinline__ void gl_lds16(const __bf16* g, __bf16* l) {
    __builtin_amdgcn_global_load_lds(
        (const __attribute__((address_space(1))) unsigned int*)g,
        (__attribute__((address_space(3))) unsigned int*)l, 16, 0, 0);
}

// load 8 consecutive A elements at p, as bf16x8 (f32 converts, bf16 passes through)
template <typename AT>
__device__ __forceinline__ bf16x8 loadA8(const AT* p) {
    if constexpr (sizeof(AT) == 4) {
        float4 u = *(const float4*)p;
        float4 v = *(const float4*)(p + 4);
        return (bf16x8){(__bf16)u.x, (__bf16)u.y, (__bf16)u.z, (__bf16)u.w,
                        (__bf16)v.x, (__bf16)v.y, (__bf16)v.z, (__bf16)v.w};
    } else {
        return *(const bf16x8*)p;
    }
}

// ---------------------------------------------------------------- U-set marking
__global__ __launch_bounds__(256) void mark_idx_kernel(const int* __restrict__ idx,
                                                       int* __restrict__ flagIdx,
                                                       int* __restrict__ flagU, int B) {
    int t = blockIdx.x * 256 + threadIdx.x;
    if (t < B) {
        int n = idx[t];
        flagIdx[n] = 1;
        flagU[n] = 1;
    }
}

// histogram of dst + mark sources of idx-edges (one pass over edges)
__global__ __launch_bounds__(256) void hist_mark_kernel(const int* __restrict__ esrc,
                                                        const int* __restrict__ edst,
                                                        const int* __restrict__ flagIdx,
                                                        int* __restrict__ deg,
                                                        int* __restrict__ flagU, int E) {
    int e = blockIdx.x * 256 + threadIdx.x;
    if (e < E) {
        int d = edst[e];
        atomicAdd(&deg[d], 1);
        if (flagIdx[d]) flagU[esrc[e]] = 1;
    }
}

// ---------------------------------------------------------------- scan (1 block, 8/thread) + U-compaction tail
__global__ __launch_bounds__(1024) void scan8_kernel(const int* __restrict__ deg,
                                                     int* __restrict__ off, int n,
                                                     const int* __restrict__ flagU,
                                                     int* __restrict__ U,
                                                     int* __restrict__ nU) {
    __shared__ int wsum[16];
    int tid = threadIdx.x, lane = tid & 63, wid = tid >> 6;
    if (tid == 0) off[0] = 0;
    int carry = 0;
    int nchunk = (n + 8191) >> 13;
    for (int c = 0; c < nchunk; ++c) {
        int base = (c << 13) + tid * 8;
        int4 a = *(const int4*)(deg + base);
        int4 b = *(const int4*)(deg + base + 4);
        int s[8];
        s[0] = a.x; s[1] = s[0] + a.y; s[2] = s[1] + a.z; s[3] = s[2] + a.w;
        s[4] = s[3] + b.x; s[5] = s[4] + b.y; s[6] = s[5] + b.z; s[7] = s[6] + b.w;
        int x = s[7];
        for (int o = 1; o < 64; o <<= 1) {
            int t = __shfl_up(x, o, 64);
            if (lane >= o) x += t;
        }
        if (lane == 63) wsum[wid] = x;
        __syncthreads();
        if (wid == 0 && lane < 16) {
            int w = wsum[lane];
            for (int o = 1; o < 16; o <<= 1) {
                int t = __shfl_up(w, o, 64);
                if (lane >= o) w += t;
            }
            wsum[lane] = w;
        }
        __syncthreads();
        int pre = carry + (wid ? wsum[wid - 1] : 0) + (x - s[7]);
#pragma unroll
        for (int i = 0; i < 8; ++i)
            if (base + i < n) off[base + i + 1] = pre + s[i];
        carry += wsum[15];
        __syncthreads();
    }
    // fused U-compaction (independent of the scan, needs only flagU)
    for (int i = tid; i < n; i += 1024)
        if (flagU[i]) U[atomicAdd(nU, 1)] = i;
}

__global__ __launch_bounds__(256) void scatter_kernel(const int* __restrict__ src,
                                                      const int* __restrict__ dst,
                                                      const int* __restrict__ off,
                                                      int* __restrict__ cursor,
                                                      int* __restrict__ srcs, int E) {
    int e = blockIdx.x * 256 + threadIdx.x;
    if (e < E) {
        int d = dst[e];
        int p = off[d] + atomicAdd(&cursor[d], 1);
        srcs[p] = src[e];
    }
}

// ---------------------------------------------------------------- weight prep
// w0t: [512,1024] bf16 rows ordered k,v,q,s ; w1t: [512,128] ; b0,b1: [512] f32 same order
__global__ __launch_bounds__(256) void pack_w_kernel(const float* __restrict__ wq0, const float* __restrict__ wk0,
                                                     const float* __restrict__ wv0, const float* __restrict__ ws0,
                                                     const float* __restrict__ wq1, const float* __restrict__ wk1,
                                                     const float* __restrict__ wv1, const float* __restrict__ ws1,
                                                     const float* __restrict__ bq0, const float* __restrict__ bk0,
                                                     const float* __restrict__ bv0, const float* __restrict__ bs0,
                                                     const float* __restrict__ bq1, const float* __restrict__ bk1,
                                                     const float* __restrict__ bv1, const float* __restrict__ bs1,
                                                     __bf16* __restrict__ w0t, __bf16* __restrict__ w1t,
                                                     float* __restrict__ b0, float* __restrict__ b1) {
    int i = blockIdx.x * 256 + threadIdx.x;
    const int S0 = 512 * 1024, S1 = 512 * 128;
    if (i < S0) {
        int n = i >> 10, k = i & 1023;
        int sel = n >> 7, c = n & 127;
        const float* w = (sel == 0) ? wk0 : (sel == 1) ? wv0 : (sel == 2) ? wq0 : ws0;
        w0t[i] = (__bf16)w[(size_t)k * 128 + c];
    } else if (i < S0 + S1) {
        int j = i - S0;
        int n = j >> 7, k = j & 127;
        int sel = n >> 7, c = n & 127;
        const float* w = (sel == 0) ? wk1 : (sel == 1) ? wv1 : (sel == 2) ? wq1 : ws1;
        w1t[j] = (__bf16)w[(size_t)k * 128 + c];
    } else if (i < S0 + S1 + 512) {
        int t = i - S0 - S1;
        int sel = t >> 7, c = t & 127;
        const float* b = (sel == 0) ? bk0 : (sel == 1) ? bv0 : (sel == 2) ? bq0 : bs0;
        b0[t] = b[c];
    } else if (i < S0 + S1 + 1024) {
        int t = i - S0 - S1 - 512;
        int sel = t >> 7, c = t & 127;
        const float* b = (sel == 0) ? bk1 : (sel == 1) ? bv1 : (sel == 2) ? bq1 : bs1;
        b1[t] = b[c];
    }
}

// ---------------------------------------------------------------- dual-sector MFMA GEMM
// sector = blockIdx.x>>1 : 0 -> Bt rows [0,256)   -> outb (bf16), rows rl0/n0
//                          1 -> Bt rows [256,512) -> outf (f32),  rows rl1/n1
// nbase = (blockIdx.x&1)*128. A f32 (layer0, cast fused) or bf16 (layer1).
// 512 threads = 8 waves in 2(m)x4(n); wave tile 64x32 -> acc 4x2 f32x4 = 32 AGPR/wave
// (half of the 4-wave variant: more resident waves -> more latency overlap).
// Single-buffered 2-barrier K-loop (m97 structure; explicit dbuf regressed, R4).
template <typename AT>
__global__ __launch_bounds__(512) void gemm_dual_kernel(const AT* __restrict__ A,
                                                        const __bf16* __restrict__ Bt,
                                                        const float* __restrict__ bias,
                                                        __bf16* __restrict__ outb,
                                                        float* __restrict__ outf,
                                                        const int* __restrict__ rl0,
                                                        const int* __restrict__ np0, int ns0,
                                                        const int* __restrict__ rl1,
                                                        const int* __restrict__ np1, int ns1,
                                                        int K) {
    __shared__ __align__(16) __bf16 Asl[128 * 32];
    __shared__ __align__(16) __bf16 Bsl[128 * 32];
    const int sector = blockIdx.x >> 1;
    const int nbase = (blockIdx.x & 1) << 7;
    const int* rowlist = sector ? rl1 : rl0;
    const int* nptr = sector ? np1 : np0;
    const int nrows = nptr ? *nptr : (sector ? ns1 : ns0);
    if (nrows <= 0) return;
    const __bf16* BT = Bt + (size_t)(sector ? 256 : 0) * K;
    const float* bs = bias + (sector ? 256 : 0);
    const int ntiles = (nrows + 127) >> 7;

    const int tid = threadIdx.x;
    const int lane = tid & 63, wid = tid >> 6;   // wid 0..7
    const int wm = wid >> 2, wn = wid & 3;       // 2 x 4 wave grid
    const int fr = lane & 15, quad = lane >> 4;
    const int rr = tid >> 2;                     // 0..127 (all rows in one round)
    const int kc8 = (tid & 3) << 3;              // k-offset elements (16B per lane)

    // B staging: one global_load_lds per wave (wave w covers rows 16w..16w+15)
    const __bf16* gB = BT + (size_t)(nbase + rr) * K + kc8;
    __bf16* ldsB = Bsl + (size_t)(wid << 4) * 32;  // wave-uniform base + lane*16B

    for (int mt = blockIdx.y; mt < ntiles; mt += gridDim.y) {
        const int mbase = mt << 7;
        int lr = mbase + rr;
        if (lr >= nrows) lr = nrows - 1;
        const int gr = rowlist ? rowlist[lr] : lr;
        const AT* gA = A + (size_t)gr * K + kc8;

        f32x4 acc[4][2];
#pragma unroll
        for (int i = 0; i < 4; i++)
#pragma unroll
            for (int j = 0; j < 2; j++) acc[i][j] = (f32x4){0.f, 0.f, 0.f, 0.f};

        for (int k0 = 0; k0 < K; k0 += 32) {
            __syncthreads();
            gl_lds16(gB + k0, ldsB);
            bf16x8 a8 = loadA8(gA + k0);
            *(bf16x8*)&Asl[rr * 32 + kc8] = a8;
            __syncthreads();
            bf16x8 af[4], bfr[2];
#pragma unroll
            for (int mi = 0; mi < 4; mi++)
                af[mi] = *(const bf16x8*)&Asl[(wm * 64 + mi * 16 + fr) * 32 + quad * 8];
#pragma unroll
            for (int ni = 0; ni < 2; ni++)
                bfr[ni] = *(const bf16x8*)&Bsl[(wn * 32 + ni * 16 + fr) * 32 + quad * 8];
#pragma unroll
            for (int mi = 0; mi < 4; mi++)
#pragma unroll
                for (int ni = 0; ni < 2; ni++)
                    acc[mi][ni] = __builtin_amdgcn_mfma_f32_16x16x32_bf16(af[mi], bfr[ni], acc[mi][ni], 0, 0, 0);
        }

#pragma unroll
        for (int mi = 0; mi < 4; mi++)
#pragma unroll
            for (int ni = 0; ni < 2; ni++) {
                int rl = wm * 64 + mi * 16 + quad * 4;
                int cl = wn * 32 + ni * 16 + fr;
                float b = bs[nbase + cl];
                int gcol = nbase + cl;
#pragma unroll
                for (int r = 0; r < 4; r++) {
                    int lr2 = mbase + rl + r;
                    if (lr2 < nrows) {
                        int gr2 = rowlist ? rowlist[lr2] : lr2;
                        float v = acc[mi][ni][r] + b;
                        if (sector == 0) outb[(size_t)gr2 * 256 + gcol] = (__bf16)v;
                        else             outf[(size_t)gr2 * 256 + gcol] = v;
                    }
                }
            }
        __syncthreads();
    }
}

// ---------------------------------------------------------------- per-dst online-softmax attention
// q,s f32 from qs[node][0:128 / 128:256]; k,v bf16 from kvb[src][0:128 / 128:256].
// mode 1: out = relu(agg+s) bf16 by node ; mode 0: out f32 by slot.
__global__ __launch_bounds__(256) void attn_kernel(const float* __restrict__ qs,
                                                   const __bf16* __restrict__ kvb,
                                                   const int* __restrict__ off,
                                                   const int* __restrict__ srcs,
                                                   const int* __restrict__ nodelist,
                                                   const int* __restrict__ nptr, int nstatic,
                                                   __bf16* __restrict__ outb,
                                                   float* __restrict__ outf, int mode) {
    int n = nptr ? *nptr : nstatic;
    int lane = threadIdx.x & 63;
    int w0 = blockIdx.x * 4 + (threadIdx.x >> 6);
    int nw = gridDim.x * 4;
    const float scale = 0.08838834764831845f;  // 1/sqrt(128)
    for (int w = w0; w < n; w += nw) {
        int node = nodelist ? nodelist[w] : w;
        const float* bq = qs + (size_t)node * 256;
        float2 q = *(const float2*)(bq + 2 * lane);
        float2 s = *(const float2*)(bq + 128 + 2 * lane);
        int e0 = off[node], e1 = off[node + 1];
        float m = -INFINITY, l = 0.f;
        float ax = 0.f, ay = 0.f;
        bf16x2 kc = {(__bf16)0.f, (__bf16)0.f}, vc = kc;
        if (e0 < e1) {
            const __bf16* p = kvb + (size_t)srcs[e0] * 256;
            kc = *(const bf16x2*)(p + 2 * lane);
            vc = *(const bf16x2*)(p + 128 + 2 * lane);
        }
        for (int e = e0; e < e1; ++e) {
            bf16x2 kn = {(__bf16)0.f, (__bf16)0.f}, vn = kn;
            if (e + 1 < e1) {  // prefetch next edge before the serial chain
                const __bf16* p = kvb + (size_t)srcs[e + 1] * 256;
                kn = *(const bf16x2*)(p + 2 * lane);
                vn = *(const bf16x2*)(p + 128 + 2 * lane);
            }
            float t = q.x * (float)kc.x + q.y * (float)kc.y;
#pragma unroll
            for (int o = 32; o > 0; o >>= 1) t += __shfl_xor(t, o, 64);
            float sc = t * scale;
            float mn = fmaxf(m, sc);
            float al = __expf(m - mn);
            float ee = __expf(sc - mn);
            ax = ax * al + ee * (float)vc.x;
            ay = ay * al + ee * (float)vc.y;
            l = l * al + ee;
            m = mn;
            kc = kn; vc = vn;
        }
        float inv = 1.f / (l + 1e-16f);
        float ox = ax * inv + s.x, oy = ay * inv + s.y;
        if (mode) {
            bf16x2 o2 = {(__bf16)fmaxf(ox, 0.f), (__bf16)fmaxf(oy, 0.f)};
            *(bf16x2*)(outb + (size_t)node * 128 + 2 * lane) = o2;
        } else {
            float2 o2 = {fmaxf(ox, 0.f), fmaxf(oy, 0.f)};
            *(float2*)(outf + (size_t)w * 128 + 2 * lane) = o2;
        }
    }
}

// ---------------------------------------------------------------- MLP head: 128 -> 128 -> 64 -> 1 sigmoid
__global__ __launch_bounds__(128) void mlp_kernel(const float* __restrict__ hbuf,
                                                  const float* __restrict__ mw1, const float* __restrict__ mb1,
                                                  const float* __restrict__ mw2, const float* __restrict__ mb2,
                                                  const float* __restrict__ mw3, const float* __restrict__ mb3,
                                                  float* __restrict__ out, int B) {
    int b = blockIdx.x;
    int t = threadIdx.x;
    if (b >= B) return;
    __shared__ float xr[128], z1[128], z2[64];
    xr[t] = hbuf[(size_t)b * 128 + t];
    __syncthreads();
    float a1 = mb1[t];
#pragma unroll 8
    for (int k = 0; k < 128; ++k) a1 += xr[k] * mw1[k * 128 + t];
    z1[t] = fmaxf(a1, 0.f);
    __syncthreads();
    if (t < 64) {
        float a2 = mb2[t];
#pragma unroll 8
        for (int k = 0; k < 128; ++k) a2 += z1[k] * mw2[k * 64 + t];
        z2[t] = fmaxf(a2, 0.f);
    }
    __syncthreads();
    if (t < 64) {
        float p = z2[t] * mw3[t];
#pragma unroll
        for (int o = 32; o > 0; o >>= 1) p += __shfl_xor(p, o, 64);
        if (t == 0) out[b] = 1.f / (1.f + __expf(-(p + mb3[0])));
    }
}

// ---------------------------------------------------------------- launch
extern "C" void kernel_launch(void* const* d_in, const int* in_sizes, int n_in,
                              void* d_out, int out_size, void* d_ws, size_t ws_size,
                              hipStream_t stream) {
    const float* x   = (const float*)d_in[0];
    const int*   ei  = (const int*)d_in[1];
    const int*   idx = (const int*)d_in[2];
    const float* wq0 = (const float*)d_in[3];
    const float* wk0 = (const float*)d_in[4];
    const float* wv0 = (const float*)d_in[5];
    const float* ws0 = (const float*)d_in[6];
    const float* bq0 = (const float*)d_in[7];
    const float* bk0 = (const float*)d_in[8];
    const float* bv0 = (const float*)d_in[9];
    const float* bs0 = (const float*)d_in[10];
    const float* wq1 = (const float*)d_in[11];
    const float* wk1 = (const float*)d_in[12];
    const float* wv1 = (const float*)d_in[13];
    const float* ws1 = (const float*)d_in[14];
    const float* bq1 = (const float*)d_in[15];
    const float* bk1 = (const float*)d_in[16];
    const float* bv1 = (const float*)d_in[17];
    const float* bs1 = (const float*)d_in[18];
    const float* mw1 = (const float*)d_in[19];
    const float* mb1 = (const float*)d_in[20];
    const float* mw2 = (const float*)d_in[21];
    const float* mb2 = (const float*)d_in[22];
    const float* mw3 = (const float*)d_in[23];
    const float* mb3 = (const float*)d_in[24];
    float* out = (float*)d_out;

    const int Nn = in_sizes[0] / 1024;  // 50000
    const int E  = in_sizes[1] / 2;     // 600000
    const int B  = in_sizes[2];         // 1000
    const int* esrc = ei;
    const int* edst = ei + E;
    const int degPad = ((Nn + 8191) >> 13) << 13;

    uintptr_t base = (uintptr_t)d_ws;
    auto alloc = [&](size_t bytes) -> void* {
        uintptr_t p = (base + 255) & ~(uintptr_t)255;
        base = p + bytes;
        return (void*)p;
    };
    __bf16* kvb  = (__bf16*)alloc((size_t)Nn * 256 * 2);   // 25.6 MB; kv1b aliases (kv0 dead after attn0)
    __bf16* kv1b = kvb;
    float*  qs   = (float*)alloc((size_t)Nn * 256 * 4);    // 51.2 MB; qs1 aliases
    float*  qs1  = qs;
    __bf16* h0b  = (__bf16*)alloc((size_t)Nn * 128 * 2);   // 12.8 MB (only U rows valid)
    float*  hbuf = (float*)alloc((size_t)B * 128 * 4);
    __bf16* w0t  = (__bf16*)alloc(512 * 1024 * 2);
    __bf16* w1t  = (__bf16*)alloc(512 * 128 * 2);
    float*  b0   = (float*)alloc(512 * 4);
    float*  b1   = (float*)alloc(512 * 4);
    // zero region (one memset): deg(padded), cursor, flagIdx, flagU, nU
    int* deg     = (int*)alloc((size_t)degPad * 4);
    int* cursor  = (int*)alloc((size_t)Nn * 4);
    int* flagIdx = (int*)alloc((size_t)Nn * 4);
    int* flagU   = (int*)alloc((size_t)Nn * 4);
    int* nU      = (int*)alloc(256);
    size_t zbytes = (uintptr_t)nU + 256 - (uintptr_t)deg;
    int* off     = (int*)alloc((size_t)(Nn + 1) * 4);
    int* srcs    = (int*)alloc((size_t)E * 4);
    int* U       = (int*)alloc((size_t)Nn * 4);

    hipMemsetAsync(deg, 0, zbytes, stream);

    // ---- U set + CSR
    mark_idx_kernel<<<(B + 255) / 256, 256, 0, stream>>>(idx, flagIdx, flagU, B);
    hist_mark_kernel<<<(E + 255) / 256, 256, 0, stream>>>(esrc, edst, flagIdx, deg, flagU, E);
    scan8_kernel<<<1, 1024, 0, stream>>>(deg, off, Nn, flagU, U, nU);
    scatter_kernel<<<(E + 255) / 256, 256, 0, stream>>>(esrc, edst, off, cursor, srcs, E);

    // ---- weights
    pack_w_kernel<<<(512 * 1024 + 512 * 128 + 1024 + 255) / 256, 256, 0, stream>>>(
        wq0, wk0, wv0, ws0, wq1, wk1, wv1, ws1,
        bq0, bk0, bv0, bs0, bq1, bk1, bv1, bs1, w0t, w1t, b0, b1);

    const int mtiles = (Nn + 127) / 128;  // 391

    // ---- layer 0: sector0 = k|v all rows -> kvb(bf16); sector1 = q|s U rows -> qs(f32)
    gemm_dual_kernel<float><<<dim3(4, mtiles), 512, 0, stream>>>(x, w0t, b0, kvb, qs,
                                                                 nullptr, nullptr, Nn,
                                                                 U, nU, 0, 1024);
    attn_kernel<<<4096, 256, 0, stream>>>(qs, kvb, off, srcs, U, nU, 0, h0b, nullptr, 1);

    // ---- layer 1: sector0 = k|v U rows -> kv1b(bf16); sector1 = q|s idx rows -> qs1(f32)
    gemm_dual_kernel<__bf16><<<dim3(4, 96), 512, 0, stream>>>(h0b, w1t, b1, kv1b, qs1,
                                                              U, nU, 0,
                                                              idx, nullptr, B, 128);
    attn_kernel<<<(B + 3) / 4, 256, 0, stream>>>(qs1, kv1b, off, srcs, idx, nullptr, B, nullptr, hbuf, 0);

    // ---- MLP head
    mlp_kernel<<<B, 128, 0, stream>>>(hbuf, mw1, mb1, mw2, mb2, mw3, mb3, out, B);
}